// Round 7
// baseline (419.695 us; speedup 1.0000x reference)
//
#include <hip/hip_runtime.h>
#include <math.h>

typedef __attribute__((ext_vector_type(8))) short short8v;
typedef __attribute__((ext_vector_type(4))) float f32x4;

static __device__ __forceinline__ ushort f2bf(float x) {
  unsigned u = __builtin_bit_cast(unsigned, x);
  unsigned r = (u + 0x7fffu + ((u >> 16) & 1u)) >> 16;
  return (ushort)r;
}

__device__ __forceinline__ float gelu_f(float v) {
  float t = tanhf(0.7978845608028654f * (v + 0.044715f * v * v * v));
  return 0.5f * v * (1.0f + t);
}

// ---------------- device-scope grid barrier (all blocks co-resident) -------
__device__ __forceinline__ void gbar(int* cnt, int target) {
  __syncthreads();
  if (threadIdx.x == 0) {
    __hip_atomic_fetch_add(cnt, 1, __ATOMIC_RELEASE, __HIP_MEMORY_SCOPE_AGENT);
    while (__hip_atomic_load(cnt, __ATOMIC_ACQUIRE, __HIP_MEMORY_SCOPE_AGENT) < target) {
      __builtin_amdgcn_s_sleep(2);
    }
  }
  __syncthreads();
}

// ---------------- convert / transpose weights to bf16 + LN1 + bar reset ----
struct CvtTasks {
  const float* src[16];
  void* dst[16];
  int rows[16], cols[16], mode[16], aux[16], end[16];
};

__global__ __launch_bounds__(256) void cvt_kernel(CvtTasks T,
    const float* __restrict__ lnx, const float* __restrict__ lng,
    const float* __restrict__ lnb, ushort* __restrict__ lnout,
    int* __restrict__ bars)
{
  if (blockIdx.x == 0 && threadIdx.x == 0) { bars[0] = 0; bars[1] = 0; }
  __shared__ ushort tile[64][65];
  int b = blockIdx.x, t = threadIdx.x;
  int ti = 0;
  while (b >= T.end[ti]) ++ti;
  int lb = b - (ti ? T.end[ti-1] : 0);
  const float* src = T.src[ti];
  int mode = T.mode[ti];
  if (mode == 0) {
    int R = T.rows[ti], C = T.cols[ti];
    int tpr = C >> 6;
    int tyy = lb / tpr, txx = lb - tyy * tpr;
    int r0 = tyy << 6, c0 = txx << 6;
    int lr = t >> 4, lc4 = (t & 15) << 2;
    #pragma unroll
    for (int i = 0; i < 4; ++i) {
      int row = i*16 + lr;
      float4 vv = *(const float4*)(src + (size_t)(r0+row)*C + c0 + lc4);
      tile[row][lc4+0] = f2bf(vv.x);
      tile[row][lc4+1] = f2bf(vv.y);
      tile[row][lc4+2] = f2bf(vv.z);
      tile[row][lc4+3] = f2bf(vv.w);
    }
    __syncthreads();
    ushort* dst = (ushort*)T.dst[ti];
    #pragma unroll
    for (int i = 0; i < 4; ++i) {
      int n = i*16 + lr;
      ushort4 o;
      o.x = tile[lc4+0][n];
      o.y = tile[lc4+1][n];
      o.z = tile[lc4+2][n];
      o.w = tile[lc4+3][n];
      *(ushort4*)(dst + (size_t)(c0+n)*R + r0 + lc4) = o;
    }
  } else if (mode == 1) {
    int idx = lb*2048 + t*8;
    float4 v0 = *(const float4*)(src + idx);
    float4 v1 = *(const float4*)(src + idx + 4);
    union { ushort u[8]; uint4 q; } pk;
    pk.u[0]=f2bf(v0.x); pk.u[1]=f2bf(v0.y); pk.u[2]=f2bf(v0.z); pk.u[3]=f2bf(v0.w);
    pk.u[4]=f2bf(v1.x); pk.u[5]=f2bf(v1.y); pk.u[6]=f2bf(v1.z); pk.u[7]=f2bf(v1.w);
    *(uint4*)((ushort*)T.dst[ti] + idx) = pk.q;
  } else if (mode == 2) {
    if (t < T.cols[ti]) {
      float* d = (float*)T.dst[ti];
      for (int r = 0; r < T.rows[ti]; ++r)
        d[(size_t)(2*r + T.aux[ti]) * T.cols[ti] + t] = src[(size_t)r * T.cols[ti] + t];
    }
  } else {
    int row = lb*4 + (t >> 6);
    int lane = t & 63;
    const float* xr = lnx + (size_t)row*512 + lane*8;
    float4 a = *(const float4*)xr;
    float4 c = *(const float4*)(xr + 4);
    float s  = a.x + a.y + a.z + a.w + c.x + c.y + c.z + c.w;
    float ss = a.x*a.x + a.y*a.y + a.z*a.z + a.w*a.w
             + c.x*c.x + c.y*c.y + c.z*c.z + c.w*c.w;
    #pragma unroll
    for (int off = 32; off > 0; off >>= 1) {
      s  += __shfl_xor(s, off);
      ss += __shfl_xor(ss, off);
    }
    float mu  = s * (1.0f/512.0f);
    float var = ss * (1.0f/512.0f) - mu*mu;
    float rstd = rsqrtf(var + 1e-5f);
    float4 g0 = *(const float4*)(lng + lane*8), g1 = *(const float4*)(lng + lane*8 + 4);
    float4 b0 = *(const float4*)(lnb + lane*8), b1 = *(const float4*)(lnb + lane*8 + 4);
    union { ushort u[8]; uint4 v; } pk;
    pk.u[0] = f2bf((a.x-mu)*rstd*g0.x + b0.x);
    pk.u[1] = f2bf((a.y-mu)*rstd*g0.y + b0.y);
    pk.u[2] = f2bf((a.z-mu)*rstd*g0.z + b0.z);
    pk.u[3] = f2bf((a.w-mu)*rstd*g0.w + b0.w);
    pk.u[4] = f2bf((c.x-mu)*rstd*g1.x + b1.x);
    pk.u[5] = f2bf((c.y-mu)*rstd*g1.y + b1.y);
    pk.u[6] = f2bf((c.z-mu)*rstd*g1.z + b1.z);
    pk.u[7] = f2bf((c.w-mu)*rstd*g1.w + b1.w);
    *(uint4*)(lnout + (size_t)row*512 + lane*8) = pk.v;
  }
}

// ---------------- MFMA bf16 GEMM body: 64x64 tile, BK=64, smem passed in ---
template<bool OUT_BF16, bool GELU_>
__device__ __forceinline__ void gemm64_body(char* smem,
    const ushort* __restrict__ A, int lda,
    const ushort* __restrict__ Bt, int ldb,
    const float* __restrict__ bias,
    void* __restrict__ Cout, int ldc,
    int ksteps, int bm, int bn)
{
  char* asB = smem;           // 64 rows x 128B
  char* bsB = smem + 8192;
  int tid = threadIdx.x;
  int lane = tid & 63, wid = tid >> 6;
  int wr = wid >> 1, wc = wid & 1;
  int l15 = lane & 15, kg = lane >> 4;
  f32x4 acc[2][2] = {};
  const ushort* Ab = A + (size_t)bm * lda;
  const ushort* Bb = Bt + (size_t)bn * ldb;
  int r0 = tid >> 3;          // 0..31
  int c16 = tid & 7;
  int wb0 = r0*128 + ((c16*16) ^ ((r0 & 7) << 4));
  int wb1 = (r0+32)*128 + ((c16*16) ^ ((r0 & 7) << 4));
  for (int ks = 0; ks < ksteps; ++ks) {
    int k0 = ks * 64;
    uint4 ra0 = *(const uint4*)(Ab + (size_t)r0*lda + k0 + c16*8);
    uint4 ra1 = *(const uint4*)(Ab + (size_t)(r0+32)*lda + k0 + c16*8);
    uint4 rb0 = *(const uint4*)(Bb + (size_t)r0*ldb + k0 + c16*8);
    uint4 rb1 = *(const uint4*)(Bb + (size_t)(r0+32)*ldb + k0 + c16*8);
    __syncthreads();
    *(uint4*)(asB + wb0) = ra0;  *(uint4*)(asB + wb1) = ra1;
    *(uint4*)(bsB + wb0) = rb0;  *(uint4*)(bsB + wb1) = rb1;
    __syncthreads();
    #pragma unroll
    for (int half = 0; half < 2; ++half) {
      int cb = half*64 + kg*16;
      short8v av[2], bv[2];
      #pragma unroll
      for (int m = 0; m < 2; ++m) {
        int r = wr*32 + m*16 + l15;
        av[m] = *(const short8v*)(asB + r*128 + (cb ^ ((r & 7) << 4)));
      }
      #pragma unroll
      for (int n = 0; n < 2; ++n) {
        int r = wc*32 + n*16 + l15;
        bv[n] = *(const short8v*)(bsB + r*128 + (cb ^ ((r & 7) << 4)));
      }
      #pragma unroll
      for (int m = 0; m < 2; ++m)
        #pragma unroll
        for (int n = 0; n < 2; ++n)
          acc[m][n] = __builtin_amdgcn_mfma_f32_16x16x32_bf16(av[m], bv[n], acc[m][n], 0, 0, 0);
    }
  }
  int orow0 = bm + wr*32 + kg*4;
  int ocol0 = bn + wc*32 + l15;
  #pragma unroll
  for (int m = 0; m < 2; ++m) {
    #pragma unroll
    for (int r = 0; r < 4; ++r) {
      int row = orow0 + m*16 + r;
      #pragma unroll
      for (int n = 0; n < 2; ++n) {
        int col = ocol0 + n*16;
        float val = acc[m][n][r];
        if (bias) val += bias[col];
        if (GELU_) val = gelu_f(val);
        if (OUT_BF16) ((ushort*)Cout)[(size_t)row*ldc + col] = f2bf(val);
        else          ((float*)Cout)[(size_t)row*ldc + col]  = val;
      }
    }
  }
}

// ---------------- mega1: qkv+Pqk GEMMs | barrier | u-GEMM+addhead+cvec -----
__global__ __launch_bounds__(256, 2) void mega1(
    const ushort* __restrict__ h, const ushort* __restrict__ WcT,
    const float* __restrict__ bc, float* __restrict__ qkv,
    const ushort* __restrict__ absb, const ushort* __restrict__ Wp,
    const float* __restrict__ bqk, float* __restrict__ Pqk,
    const float* __restrict__ rel_bias, const float* __restrict__ brk,
    const ushort* __restrict__ Wrkb, float* __restrict__ u,
    float* __restrict__ cvec, int* __restrict__ bars)
{
  __shared__ __align__(16) char smem[16384];
  int blk = blockIdx.x;
  int tid = threadIdx.x;

  // ---- phase 1: qkv (384 tiles) + Pqk (128 tiles) ----
  if (blk < 384) {
    int z = blk >> 7, rem = blk & 127;
    int bn = (rem & 7) * 64, bm = (rem >> 3) * 64;
    gemm64_body<false,false>(smem, h, 512, WcT + (size_t)z*262144, 512,
        bc + z*512, qkv + (size_t)z*524288, 512, 8, bm, bn);
  } else {
    int t2 = blk - 384;
    int z = t2 >> 5, rem = t2 & 31;
    int bn = (rem & 1) * 64, bm = (rem >> 1) * 64;
    gemm64_body<false,false>(smem, absb + (size_t)(z >> 1)*524288, 512,
        Wp + (size_t)z*65536, 512, bqk + z*128,
        Pqk + (size_t)z*131072, 128, 8, bm, bn);
  }

  gbar(bars, 512);

  // ---- phase 2: u-GEMM (256) + addhead (1024) + cvec (1024) tasks ----
  const float* q = qkv;
  const float* k = qkv + 524288;
  for (int t = blk; t < 2304; t += 512) {
    if (t < 256) {
      int l = t >> 7;
      int rem = t & 127;
      int bm = (rem >> 3) * 64;
      int bn = (rem & 7) * 64;
      char* asB = smem;
      char* bsB = smem + 8192;
      int lane = tid & 63, wid = tid >> 6;
      int wr = wid >> 1, wc = wid & 1;
      int l15 = lane & 15, kg = lane >> 4;
      f32x4 acc[2][2] = {};
      const ushort* Bb = Wrkb + (size_t)l*65536 + (size_t)bn*128;
      int r0 = tid >> 3, c16 = tid & 7;
      int wb0 = r0*128 + ((c16*16) ^ ((r0 & 7) << 4));
      int wb1 = (r0+32)*128 + ((c16*16) ^ ((r0 & 7) << 4));
      const float* rbp = rel_bias + l*128;
      #pragma unroll
      for (int ks = 0; ks < 2; ++ks) {
        int k0 = ks * 64;
        uint4 ra[2], rb[2];
        #pragma unroll
        for (int i = 0; i < 2; ++i) {
          int m = bm + r0 + i*32;
          int e0 = k0 + c16*8;
          const float* qp = q + (size_t)m*512 + (2+l)*128 + e0;
          float4 qa = *(const float4*)qp;
          float4 qb = *(const float4*)(qp + 4);
          float4 rr0 = *(const float4*)(rbp + e0);
          float4 rr1 = *(const float4*)(rbp + e0 + 4);
          union { ushort s[8]; uint4 v; } pk;
          pk.s[0]=f2bf(qa.x+rr0.x); pk.s[1]=f2bf(qa.y+rr0.y);
          pk.s[2]=f2bf(qa.z+rr0.z); pk.s[3]=f2bf(qa.w+rr0.w);
          pk.s[4]=f2bf(qb.x+rr1.x); pk.s[5]=f2bf(qb.y+rr1.y);
          pk.s[6]=f2bf(qb.z+rr1.z); pk.s[7]=f2bf(qb.w+rr1.w);
          ra[i] = pk.v;
          rb[i] = *(const uint4*)(Bb + (size_t)(r0 + i*32)*128 + k0 + c16*8);
        }
        __syncthreads();
        *(uint4*)(asB + wb0) = ra[0];  *(uint4*)(asB + wb1) = ra[1];
        *(uint4*)(bsB + wb0) = rb[0];  *(uint4*)(bsB + wb1) = rb[1];
        __syncthreads();
        #pragma unroll
        for (int half = 0; half < 2; ++half) {
          int cb = half*64 + kg*16;
          short8v av[2], bv[2];
          #pragma unroll
          for (int m = 0; m < 2; ++m) {
            int r = wr*32 + m*16 + l15;
            av[m] = *(const short8v*)(asB + r*128 + (cb ^ ((r & 7) << 4)));
          }
          #pragma unroll
          for (int n = 0; n < 2; ++n) {
            int r = wc*32 + n*16 + l15;
            bv[n] = *(const short8v*)(bsB + r*128 + (cb ^ ((r & 7) << 4)));
          }
          #pragma unroll
          for (int m = 0; m < 2; ++m)
            #pragma unroll
            for (int n = 0; n < 2; ++n)
              acc[m][n] = __builtin_amdgcn_mfma_f32_16x16x32_bf16(av[m], bv[n], acc[m][n], 0, 0, 0);
        }
      }
      float* Cz = u + (size_t)l*524288;
      int orow0 = bm + wr*32 + kg*4;
      int ocol0 = bn + wc*32 + l15;
      #pragma unroll
      for (int m = 0; m < 2; ++m)
        #pragma unroll
        for (int r = 0; r < 4; ++r) {
          int row = orow0 + m*16 + r;
          #pragma unroll
          for (int n = 0; n < 2; ++n)
            Cz[(size_t)row*512 + ocol0 + n*16] = acc[m][n][r];
        }
    } else if (t < 1280) {
      int idx = (t - 256)*256 + tid;
      int dk = idx & 127;
      int rest = idx >> 7;
      int m = rest & 1023;
      int a = rest >> 10;
      Pqk[idx + a*131072]     += q[(size_t)m*512 + a*128 + dk];
      Pqk[idx + (a+1)*131072] += k[(size_t)m*512 + a*128 + dk];
    } else {
      int row = (t - 1280)*2 + (tid >> 7);
      int l = row >> 10, m = row & 1023;
      int tt = tid & 127, hf = tid >> 7;
      float val = q[(size_t)m*512 + (2+l)*128 + tt] + rel_bias[l*128 + tt];
      float p = brk[l*128 + tt] * val;
      #pragma unroll
      for (int off = 32; off > 0; off >>= 1) p += __shfl_xor(p, off);
      __shared__ float red[2][2];
      if ((tid & 63) == 0) red[hf][(tid >> 6) & 1] = p;
      __syncthreads();
      if (tt == 0) cvec[row] = red[hf][0] + red[hf][1];
      __syncthreads();
    }
  }
}

// ---------------- fused attention: rel stream (blk<2048) + abs (blk>=2048) -
__global__ __launch_bounds__(256) void attn_kernel(
    const float* __restrict__ rk, const float* __restrict__ u,
    const float* __restrict__ q, const float* __restrict__ k,
    const float* __restrict__ v, const float* __restrict__ cvec,
    const float* __restrict__ Pqk, const int* __restrict__ mask,
    ushort* __restrict__ attnob)
{
  int blk = blockIdx.x;
  int tid = threadIdx.x;
  if (blk < 2048) {
    int i = blk & 127, b = (blk >> 7) & 7, l = blk >> 10, h = 2 + l;
    int m_i = b*128 + i;
    __shared__ float qs[128], sc[128], ps[128], red[64], pvs[2][128], stat[2];
    int wave = tid >> 6, lane = tid & 63;
    const float* ur = u + ((size_t)l*1024 + m_i)*512 + lane*8;
    float4 uu0 = *(const float4*)ur;
    float4 uu1 = *(const float4*)(ur + 4);
    if (tid < 128) qs[tid] = q[(size_t)m_i*512 + h*128 + tid];
    __syncthreads();
    float xq0 = qs[lane*2], xq1 = qs[lane*2+1];
    const float* base = rk + (size_t)blk*65536 + lane*8;
    const float* kb = k + (size_t)(b*128)*512 + h*128 + lane*2;
    #pragma unroll 2
    for (int jj = 0; jj < 32; ++jj) {
      int j = wave*32 + jj;
      const float* r = base + (size_t)j*512;
      float4 r0 = *(const float4*)r;
      float4 r1 = *(const float4*)(r + 4);
      float2 kk = *(const float2*)(kb + (size_t)j*512);
      float s = r0.x*uu0.x + r0.y*uu0.y + r0.z*uu0.z + r0.w*uu0.w
              + r1.x*uu1.x + r1.y*uu1.y + r1.z*uu1.z + r1.w*uu1.w
              + kk.x*xq0 + kk.y*xq1;
      #pragma unroll
      for (int off = 32; off > 0; off >>= 1) s += __shfl_xor(s, off);
      if (lane == 0) sc[j] = s;
    }
    __syncthreads();
    if (tid < 128) {
      float sv = (sc[tid] + cvec[l*1024 + m_i]) * 0.088388347648318447f;
      if (mask[((size_t)(b*128) + i)*128 + tid] == 0) sv = -1e9f;
      sc[tid] = sv;
    }
    __syncthreads();
    if (tid < 64) red[tid] = fmaxf(sc[tid], sc[tid+64]);
    __syncthreads();
    if (tid < 64) {
      float m = red[tid];
      #pragma unroll
      for (int off = 32; off > 0; off >>= 1) m = fmaxf(m, __shfl_xor(m, off));
      if (tid == 0) stat[0] = m;
    }
    __syncthreads();
    if (tid < 128) ps[tid] = __expf(sc[tid] - stat[0]);
    __syncthreads();
    if (tid < 64) red[tid] = ps[tid] + ps[tid+64];
    __syncthreads();
    if (tid < 64) {
      float s = red[tid];
      #pragma unroll
      for (int off = 32; off > 0; off >>= 1) s += __shfl_xor(s, off);
      if (tid == 0) stat[1] = 1.0f / s;
    }
    __syncthreads();
    int hf = tid >> 7, dk = tid & 127;
    const float* vp = v + (size_t)(b*128 + hf*64)*512 + h*128 + dk;
    float o = 0.0f;
    #pragma unroll 4
    for (int jj = 0; jj < 64; ++jj) o += ps[hf*64 + jj] * vp[(size_t)jj*512];
    pvs[hf][dk] = o;
    __syncthreads();
    if (tid < 128)
      attnob[(size_t)m_i*512 + h*128 + tid] = f2bf((pvs[0][tid] + pvs[1][tid]) * stat[1]);
  } else {
    int ab = blk - 2048;
    int hf = tid >> 7, t = tid & 127;
    int i  = (ab & 63)*2 + hf;
    int bh = ab >> 6;
    int h  = bh & 1, b = bh >> 1;
    __shared__ float qsh[2][128], psh[2][128], redm[2][2], reds[2][2];
    int m_i = b*128 + i;
    qsh[hf][t] = Pqk[(size_t)(2*h)*131072 + (size_t)m_i*128 + t];
    __syncthreads();
    int m_j = b*128 + t;
    const float* krow = Pqk + (size_t)(2*h+1)*131072 + (size_t)m_j*128;
    float dot = 0.0f;
    #pragma unroll
    for (int d = 0; d < 128; d += 4) {
      float4 kv = *(const float4*)(krow + d);
      dot += kv.x*qsh[hf][d] + kv.y*qsh[hf][d+1] + kv.z*qsh[hf][d+2] + kv.w*qsh[hf][d+3];
    }
    float s = dot * 0.088388347648318447f;
    if (mask[((size_t)(b*128) + i)*128 + t] == 0) s = -1e9f;
    float mx = s;
    #pragma unroll
    for (int off = 32; off > 0; off >>= 1) mx = fmaxf(mx, __shfl_xor(mx, off));
    int w2 = (tid >> 6) & 1;
    if ((tid & 63) == 0) redm[hf][w2] = mx;
    __syncthreads();
    mx = fmaxf(redm[hf][0], redm[hf][1]);
    float e = __expf(s - mx);
    psh[hf][t] = e;
    float sum = e;
    #pragma unroll
    for (int off = 32; off > 0; off >>= 1) sum += __shfl_xor(sum, off);
    if ((tid & 63) == 0) reds[hf][w2] = sum;
    __syncthreads();
    float inv = 1.0f / (reds[hf][0] + reds[hf][1]);
    const float* vp = v + (size_t)b*65536 + h*128 + t;
    float o = 0.0f;
    #pragma unroll 4
    for (int jj = 0; jj < 128; ++jj) o += psh[hf][jj] * vp[(size_t)jj*512];
    attnob[(size_t)m_i*512 + h*128 + t] = f2bf(o * inv);
  }
}

// ---------------- mega2: Wo | ln2 | FFN1 | FFN2 | reduce_out ---------------
__global__ __launch_bounds__(256, 2) void mega2(
    const ushort* __restrict__ attnob, const ushort* __restrict__ WoT,
    float* __restrict__ wpart, const float* __restrict__ bo,
    const float* __restrict__ x, const float* __restrict__ ln2g,
    const float* __restrict__ ln2b, float* __restrict__ x1,
    ushort* __restrict__ h2, const ushort* __restrict__ W1T,
    const float* __restrict__ b1, ushort* __restrict__ f1,
    const ushort* __restrict__ W2T, float* __restrict__ fpart,
    const float* __restrict__ b2, float* __restrict__ out,
    int* __restrict__ bars)
{
  __shared__ __align__(16) char smem[16384];
  int blk = blockIdx.x;
  int tid = threadIdx.x;

  // ---- P1: Wo split-K4 (z,8x16) ----
  {
    int z = blk >> 7, rem = blk & 127;
    int bn = (rem & 7) * 64, bm = (rem >> 3) * 64;
    gemm64_body<false,false>(smem, attnob + (size_t)z*128, 512,
        WoT + (size_t)z*128, 512, nullptr,
        wpart + (size_t)z*524288, 512, 2, bm, bn);
  }
  gbar(bars, 512);

  // ---- P2: splitK-reduce + bo + residual(x) + LN2 (blocks 0..255) ----
  if (blk < 256) {
    int gid = blk*256 + tid;
    int row = gid >> 6, lane = tid & 63;
    size_t off = (size_t)row*512 + lane*8;
    float4 a = *(const float4*)(x + off);
    float4 c = *(const float4*)(x + off + 4);
    #pragma unroll
    for (int sk = 0; sk < 4; ++sk) {
      float4 p0 = *(const float4*)(wpart + (size_t)sk*524288 + off);
      float4 p1 = *(const float4*)(wpart + (size_t)sk*524288 + off + 4);
      a.x += p0.x; a.y += p0.y; a.z += p0.z; a.w += p0.w;
      c.x += p1.x; c.y += p1.y; c.z += p1.z; c.w += p1.w;
    }
    float4 bo0 = *(const float4*)(bo + lane*8);
    float4 bo1 = *(const float4*)(bo + lane*8 + 4);
    a.x += bo0.x; a.y += bo0.y; a.z += bo0.z; a.w += bo0.w;
    c.x += bo1.x; c.y += bo1.y; c.z += bo1.z; c.w += bo1.w;
    *(float4*)(x1 + off) = a;
    *(float4*)(x1 + off + 4) = c;
    float s  = a.x + a.y + a.z + a.w + c.x + c.y + c.z + c.w;
    float ss = a.x*a.x + a.y*a.y + a.z*a.z + a.w*a.w
             + c.x*c.x + c.y*c.y + c.z*c.z + c.w*c.w;
    #pragma unroll
    for (int off2 = 32; off2 > 0; off2 >>= 1) {
      s  += __shfl_xor(s, off2);
      ss += __shfl_xor(ss, off2);
    }
    float mu  = s * (1.0f/512.0f);
    float var = ss * (1.0f/512.0f) - mu*mu;
    float rstd = rsqrtf(var + 1e-5f);
    float4 g0 = *(const float4*)(ln2g + lane*8), g1 = *(const float4*)(ln2g + lane*8 + 4);
    float4 b0 = *(const float4*)(ln2b + lane*8), b1v = *(const float4*)(ln2b + lane*8 + 4);
    union { ushort u[8]; uint4 v; } pk;
    pk.u[0] = f2bf((a.x-mu)*rstd*g0.x + b0.x);
    pk.u[1] = f2bf((a.y-mu)*rstd*g0.y + b0.y);
    pk.u[2] = f2bf((a.z-mu)*rstd*g0.z + b0.z);
    pk.u[3] = f2bf((a.w-mu)*rstd*g0.w + b0.w);
    pk.u[4] = f2bf((c.x-mu)*rstd*g1.x + b1v.x);
    pk.u[5] = f2bf((c.y-mu)*rstd*g1.y + b1v.y);
    pk.u[6] = f2bf((c.z-mu)*rstd*g1.z + b1v.z);
    pk.u[7] = f2bf((c.w-mu)*rstd*g1.w + b1v.w);
    *(uint4*)(h2 + off) = pk.v;
  }
  gbar(bars, 1024);

  // ---- P3: FFN1 + GELU (32x16) ----
  {
    int bn = (blk & 31) * 64, bm = (blk >> 5) * 64;
    gemm64_body<true,true>(smem, h2, 512, W1T, 512, b1, f1, 2048, 8, bm, bn);
  }
  gbar(bars, 1536);

  // ---- P4: FFN2 split-K4 (z,8x16) ----
  {
    int z = blk >> 7, rem = blk & 127;
    int bn = (rem & 7) * 64, bm = (rem >> 3) * 64;
    gemm64_body<false,false>(smem, f1 + (size_t)z*512, 2048,
        W2T + (size_t)z*512, 2048, nullptr,
        fpart + (size_t)z*524288, 512, 8, bm, bn);
  }
  gbar(bars, 2048);

  // ---- P5: reduce + b2 + residual(x1) -> out ----
  {
    int idx = blk*256 + tid;
    size_t o4 = (size_t)idx*4;
    float4 s = *(const float4*)(x1 + o4);
    #pragma unroll
    for (int sk = 0; sk < 4; ++sk) {
      float4 p = *(const float4*)(fpart + (size_t)sk*524288 + o4);
      s.x += p.x; s.y += p.y; s.z += p.z; s.w += p.w;
    }
    float4 bv = *(const float4*)(b2 + ((idx & 127)*4));
    s.x += bv.x; s.y += bv.y; s.z += bv.z; s.w += bv.w;
    *(float4*)(out + o4) = s;
  }
}

// ---------------------------------------------------------------------------
extern "C" void kernel_launch(void* const* d_in, const int* in_sizes, int n_in,
                              void* d_out, int out_size, void* d_ws, size_t ws_size,
                              hipStream_t stream)
{
  const float* x         = (const float*)d_in[0];
  const int*   mask      = (const int*)  d_in[1];
  const float* abs_kernel= (const float*)d_in[2];
  const float* rel_kernel= (const float*)d_in[3];
  const float* Wc        = (const float*)d_in[4];
  const float* bc        = (const float*)d_in[5];
  const float* Wpq       = (const float*)d_in[6];
  const float* bpq       = (const float*)d_in[7];
  const float* Wpk       = (const float*)d_in[8];
  const float* bpk       = (const float*)d_in[9];
  const float* Wrk       = (const float*)d_in[10];
  const float* brk       = (const float*)d_in[11];
  const float* rel_bias  = (const float*)d_in[12];
  const float* Wo        = (const float*)d_in[13];
  const float* bo        = (const float*)d_in[14];
  const float* W1        = (const float*)d_in[15];
  const float* b1        = (const float*)d_in[16];
  const float* W2        = (const float*)d_in[17];
  const float* b2        = (const float*)d_in[18];
  const float* ln1g      = (const float*)d_in[19];
  const float* ln1b      = (const float*)d_in[20];
  const float* ln2g      = (const float*)d_in[21];
  const float* ln2b      = (const float*)d_in[22];

  float* ws = (float*)d_ws;
  float* q      = ws;               // 3x524288 (q|k|v)
  float* kbuf   = ws + 524288;
  float* v      = ws + 1048576;
  float* Pqk    = ws + 1572864;     // 524288
  float* u      = ws + 2097152;     // 1048576
  float* x1     = ws + 3145728;     // 524288
  float* cvec   = ws + 3670016;     // 2048
  float* bqk    = ws + 3672064;     // 512
  int*   bars   = (int*)(ws + 3672576);  // 2 counters (16-float slot)
  float* wpart  = ws + 3672592;     // 2097152 (reused as fpart)
  float* fpart  = wpart;
  ushort* bf    = (ushort*)(ws + 5769760);
  ushort* h     = bf;               // 524288
  ushort* h2    = bf + 524288;
  ushort* attnob= bf + 1048576;     // 524288
  ushort* f1    = bf + 1572864;     // 2097152
  ushort* absb  = bf + 3670016;     // 1048576
  ushort* WcT   = bf + 4718592;     // 786432
  ushort* Wp    = bf + 5505024;     // 262144
  ushort* Wrkb  = bf + 5767168;     // 131072
  ushort* WoT   = bf + 5898240;     // 262144
  ushort* W1T   = bf + 6160384;     // 1048576
  ushort* W2T   = bf + 7208960;     // 1048576
  float* out    = (float*)d_out;

  // ---- convert/transpose/LN task table ----
  CvtTasks T{};
  int nb = 0, ti = 0;
  auto addTr = [&](const float* s, ushort* d, int R, int C) {
    T.src[ti]=s; T.dst[ti]=d; T.rows[ti]=R; T.cols[ti]=C; T.mode[ti]=0; T.aux[ti]=0;
    nb += (R/64)*(C/64); T.end[ti]=nb; ++ti;
  };
  auto addCv = [&](const float* s, ushort* d, int n) {
    T.src[ti]=s; T.dst[ti]=d; T.rows[ti]=n; T.cols[ti]=0; T.mode[ti]=1; T.aux[ti]=0;
    nb += n/2048; T.end[ti]=nb; ++ti;
  };
  auto addBi = [&](const float* s, float* d, int aux) {
    T.src[ti]=s; T.dst[ti]=d; T.rows[ti]=2; T.cols[ti]=128; T.mode[ti]=2; T.aux[ti]=aux;
    nb += 1; T.end[ti]=nb; ++ti;
  };
  for (int c = 0; c < 3; ++c) addTr(Wc + (size_t)c*262144, WcT + (size_t)c*262144, 512, 512);
  addTr(Wo, WoT, 512, 512);
  addTr(W1, W1T, 512, 2048);
  addTr(W2, W2T, 2048, 512);
  for (int a = 0; a < 2; ++a) addTr(Wpq + (size_t)a*65536, Wp + (size_t)(2*a)*65536, 512, 128);
  for (int a = 0; a < 2; ++a) addTr(Wpk + (size_t)a*65536, Wp + (size_t)(2*a+1)*65536, 512, 128);
  addCv(abs_kernel, absb, 1048576);
  addCv(Wrk, Wrkb, 131072);
  addBi(bpq, bqk, 0);
  addBi(bpk, bqk, 1);
  T.src[ti]=x; T.dst[ti]=h; T.mode[ti]=3; nb += 256; T.end[ti]=nb; ++ti;

  cvt_kernel<<<nb, 256, 0, stream>>>(T, x, ln1g, ln1b, h, bars);

  // mega1: qkv+Pqk GEMMs -> barrier -> u-GEMM + addhead + cvec
  mega1<<<512, 256, 0, stream>>>(h, WcT, bc, q, absb, Wp, bqk, Pqk,
                                 rel_bias, brk, Wrkb, u, cvec, bars);

  // fused attention: rel stream + abs heads
  attn_kernel<<<3072, 256, 0, stream>>>(rel_kernel, u, q, kbuf, v, cvec, Pqk, mask, attnob);

  // mega2: Wo -> ln2 -> FFN1 -> FFN2 -> reduce_out
  mega2<<<512, 256, 0, stream>>>(attnob, WoT, wpart, bo, x, ln2g, ln2b,
                                 x1, h2, W1T, b1, f1, W2T, fpart, b2, out,
                                 bars + 1);
}

// Round 8
// 197.628 us; speedup vs baseline: 2.1237x; 2.1237x over previous
//
#include <hip/hip_runtime.h>
#include <math.h>

typedef __attribute__((ext_vector_type(8))) short short8v;
typedef __attribute__((ext_vector_type(4))) float f32x4;

static __device__ __forceinline__ ushort f2bf(float x) {
  unsigned u = __builtin_bit_cast(unsigned, x);
  unsigned r = (u + 0x7fffu + ((u >> 16) & 1u)) >> 16;
  return (ushort)r;
}

__device__ __forceinline__ float gelu_f(float v) {
  float t = tanhf(0.7978845608028654f * (v + 0.044715f * v * v * v));
  return 0.5f * v * (1.0f + t);
}

// ---------------- shared transpose tile helper (64x64 f32 -> bf16^T) -------
__device__ __forceinline__ void transpose_tile(char* shm,
    const float* __restrict__ src, ushort* __restrict__ dst,
    int R, int C, int lb)
{
  ushort (*tile)[65] = (ushort(*)[65])shm;
  int t = threadIdx.x;
  int tpr = C >> 6;
  int tyy = lb / tpr, txx = lb - tyy * tpr;
  int r0 = tyy << 6, c0 = txx << 6;
  int lr = t >> 4, lc4 = (t & 15) << 2;
  #pragma unroll
  for (int i = 0; i < 4; ++i) {
    int row = i*16 + lr;
    float4 vv = *(const float4*)(src + (size_t)(r0+row)*C + c0 + lc4);
    tile[row][lc4+0] = f2bf(vv.x);
    tile[row][lc4+1] = f2bf(vv.y);
    tile[row][lc4+2] = f2bf(vv.z);
    tile[row][lc4+3] = f2bf(vv.w);
  }
  __syncthreads();
  #pragma unroll
  for (int i = 0; i < 4; ++i) {
    int n = i*16 + lr;
    ushort4 o;
    o.x = tile[lc4+0][n];
    o.y = tile[lc4+1][n];
    o.z = tile[lc4+2][n];
    o.w = tile[lc4+3][n];
    *(ushort4*)(dst + (size_t)(c0+n)*R + r0 + lc4) = o;
  }
}

// ---------------- convert / transpose (early weights) + LN1 ----------------
struct CvtTasks {
  const float* src[16];
  void* dst[16];
  int rows[16], cols[16], mode[16], aux[16], end[16];
};

__global__ __launch_bounds__(256) void cvt_kernel(CvtTasks T,
    const float* __restrict__ lnx, const float* __restrict__ lng,
    const float* __restrict__ lnb, ushort* __restrict__ lnout)
{
  __shared__ __align__(16) char shm[8448];
  int b = blockIdx.x, t = threadIdx.x;
  int ti = 0;
  while (b >= T.end[ti]) ++ti;
  int lb = b - (ti ? T.end[ti-1] : 0);
  const float* src = T.src[ti];
  int mode = T.mode[ti];
  if (mode == 0) {
    transpose_tile(shm, src, (ushort*)T.dst[ti], T.rows[ti], T.cols[ti], lb);
  } else if (mode == 1) {
    int idx = lb*2048 + t*8;
    float4 v0 = *(const float4*)(src + idx);
    float4 v1 = *(const float4*)(src + idx + 4);
    union { ushort u[8]; uint4 q; } pk;
    pk.u[0]=f2bf(v0.x); pk.u[1]=f2bf(v0.y); pk.u[2]=f2bf(v0.z); pk.u[3]=f2bf(v0.w);
    pk.u[4]=f2bf(v1.x); pk.u[5]=f2bf(v1.y); pk.u[6]=f2bf(v1.z); pk.u[7]=f2bf(v1.w);
    *(uint4*)((ushort*)T.dst[ti] + idx) = pk.q;
  } else if (mode == 2) {
    if (t < T.cols[ti]) {
      float* d = (float*)T.dst[ti];
      for (int r = 0; r < T.rows[ti]; ++r)
        d[(size_t)(2*r + T.aux[ti]) * T.cols[ti] + t] = src[(size_t)r * T.cols[ti] + t];
    }
  } else {
    int row = lb*4 + (t >> 6);
    int lane = t & 63;
    const float* xr = lnx + (size_t)row*512 + lane*8;
    float4 a = *(const float4*)xr;
    float4 c = *(const float4*)(xr + 4);
    float s  = a.x + a.y + a.z + a.w + c.x + c.y + c.z + c.w;
    float ss = a.x*a.x + a.y*a.y + a.z*a.z + a.w*a.w
             + c.x*c.x + c.y*c.y + c.z*c.z + c.w*c.w;
    #pragma unroll
    for (int off = 32; off > 0; off >>= 1) {
      s  += __shfl_xor(s, off);
      ss += __shfl_xor(ss, off);
    }
    float mu  = s * (1.0f/512.0f);
    float var = ss * (1.0f/512.0f) - mu*mu;
    float rstd = rsqrtf(var + 1e-5f);
    float4 g0 = *(const float4*)(lng + lane*8), g1 = *(const float4*)(lng + lane*8 + 4);
    float4 b0 = *(const float4*)(lnb + lane*8), b1 = *(const float4*)(lnb + lane*8 + 4);
    union { ushort u[8]; uint4 v; } pk;
    pk.u[0] = f2bf((a.x-mu)*rstd*g0.x + b0.x);
    pk.u[1] = f2bf((a.y-mu)*rstd*g0.y + b0.y);
    pk.u[2] = f2bf((a.z-mu)*rstd*g0.z + b0.z);
    pk.u[3] = f2bf((a.w-mu)*rstd*g0.w + b0.w);
    pk.u[4] = f2bf((c.x-mu)*rstd*g1.x + b1.x);
    pk.u[5] = f2bf((c.y-mu)*rstd*g1.y + b1.y);
    pk.u[6] = f2bf((c.z-mu)*rstd*g1.z + b1.z);
    pk.u[7] = f2bf((c.w-mu)*rstd*g1.w + b1.w);
    *(uint4*)(lnout + (size_t)row*512 + lane*8) = pk.v;
  }
}

// ------- MFMA bf16 GEMM body: 64x64, BK=64, double-buffered LDS (32KB) -----
template<bool OUT_BF16, bool GELU_>
__device__ __forceinline__ void gemm64_body(char* smem,
    const ushort* __restrict__ A, int lda,
    const ushort* __restrict__ Bt, int ldb,
    const float* __restrict__ bias,
    void* __restrict__ Cout, int ldc,
    int ksteps, int bm, int bn)
{
  int tid = threadIdx.x;
  int lane = tid & 63, wid = tid >> 6;
  int wr = wid >> 1, wc = wid & 1;
  int l15 = lane & 15, kg = lane >> 4;
  f32x4 acc[2][2] = {};
  const ushort* Ab = A + (size_t)bm * lda;
  const ushort* Bb = Bt + (size_t)bn * ldb;
  int r0 = tid >> 3;          // 0..31
  int c16 = tid & 7;
  int wb0 = r0*128 + ((c16*16) ^ ((r0 & 7) << 4));
  int wb1 = (r0+32)*128 + ((c16*16) ^ ((r0 & 7) << 4));
  // prologue: stage K-step 0 into buffer 0
  uint4 ra0 = *(const uint4*)(Ab + (size_t)r0*lda + c16*8);
  uint4 ra1 = *(const uint4*)(Ab + (size_t)(r0+32)*lda + c16*8);
  uint4 rb0 = *(const uint4*)(Bb + (size_t)r0*ldb + c16*8);
  uint4 rb1 = *(const uint4*)(Bb + (size_t)(r0+32)*ldb + c16*8);
  *(uint4*)(smem + wb0) = ra0;  *(uint4*)(smem + wb1) = ra1;
  *(uint4*)(smem + 8192 + wb0) = rb0;  *(uint4*)(smem + 8192 + wb1) = rb1;
  __syncthreads();
  for (int ks = 0; ks < ksteps; ++ks) {
    char* buf = smem + (ks & 1)*16384;
    char* nxt = smem + ((ks + 1) & 1)*16384;
    bool more = (ks + 1 < ksteps);
    if (more) {
      int k0 = (ks + 1) * 64;
      ra0 = *(const uint4*)(Ab + (size_t)r0*lda + k0 + c16*8);
      ra1 = *(const uint4*)(Ab + (size_t)(r0+32)*lda + k0 + c16*8);
      rb0 = *(const uint4*)(Bb + (size_t)r0*ldb + k0 + c16*8);
      rb1 = *(const uint4*)(Bb + (size_t)(r0+32)*ldb + k0 + c16*8);
    }
    char* asB = buf;
    char* bsB = buf + 8192;
    #pragma unroll
    for (int half = 0; half < 2; ++half) {
      int cb = half*64 + kg*16;
      short8v av[2], bv[2];
      #pragma unroll
      for (int m = 0; m < 2; ++m) {
        int r = wr*32 + m*16 + l15;
        av[m] = *(const short8v*)(asB + r*128 + (cb ^ ((r & 7) << 4)));
      }
      #pragma unroll
      for (int n = 0; n < 2; ++n) {
        int r = wc*32 + n*16 + l15;
        bv[n] = *(const short8v*)(bsB + r*128 + (cb ^ ((r & 7) << 4)));
      }
      #pragma unroll
      for (int m = 0; m < 2; ++m)
        #pragma unroll
        for (int n = 0; n < 2; ++n)
          acc[m][n] = __builtin_amdgcn_mfma_f32_16x16x32_bf16(av[m], bv[n], acc[m][n], 0, 0, 0);
    }
    if (more) {
      *(uint4*)(nxt + wb0) = ra0;  *(uint4*)(nxt + wb1) = ra1;
      *(uint4*)(nxt + 8192 + wb0) = rb0;  *(uint4*)(nxt + 8192 + wb1) = rb1;
    }
    __syncthreads();
  }
  int orow0 = bm + wr*32 + kg*4;
  int ocol0 = bn + wc*32 + l15;
  #pragma unroll
  for (int m = 0; m < 2; ++m) {
    #pragma unroll
    for (int r = 0; r < 4; ++r) {
      int row = orow0 + m*16 + r;
      #pragma unroll
      for (int n = 0; n < 2; ++n) {
        int col = ocol0 + n*16;
        float val = acc[m][n][r];
        if (bias) val += bias[col];
        if (GELU_) val = gelu_f(val);
        if (OUT_BF16) ((ushort*)Cout)[(size_t)row*ldc + col] = f2bf(val);
        else          ((float*)Cout)[(size_t)row*ldc + col]  = val;
      }
    }
  }
}

// generic z-batched / split-K wrapper
template<bool OUT_BF16, bool GELU_>
__global__ __launch_bounds__(256) void g64(
    const ushort* __restrict__ A, int lda, long Abatch,
    const ushort* __restrict__ Bt, int ldb, long Bbatch,
    const float* __restrict__ bias, int biasStride,
    void* __restrict__ C, int ldc, long Cbatch,
    int ksteps)
{
  __shared__ __align__(16) char smem[32768];
  int z = blockIdx.z;
  const float* bz = bias ? bias + (size_t)z * biasStride : nullptr;
  void* Cz = OUT_BF16 ? (void*)((ushort*)C + (size_t)z*Cbatch)
                      : (void*)((float*)C + (size_t)z*Cbatch);
  gemm64_body<OUT_BF16, GELU_>(smem, A + (size_t)z*Abatch, lda,
      Bt + (size_t)z*Bbatch, ldb, bz, Cz, ldc, ksteps,
      blockIdx.y*64, blockIdx.x*64);
}

// grouped qkv (z<3, N=512) + Pqk (z in 3..6, N=128)
__global__ __launch_bounds__(256) void qkvp_gemm(
    const ushort* __restrict__ h, const ushort* __restrict__ WcT,
    const float* __restrict__ bc, float* __restrict__ qkv,
    const ushort* __restrict__ absb, const ushort* __restrict__ Wp,
    const float* __restrict__ bqk, float* __restrict__ Pqk)
{
  __shared__ __align__(16) char smem[32768];
  int z = blockIdx.z;
  const ushort *A, *Bt;
  const float* bias;
  float* C;
  int ldc;
  if (z < 3) {
    A = h; Bt = WcT + (size_t)z*262144; bias = bc + z*512;
    C = qkv + (size_t)z*524288; ldc = 512;
  } else {
    if (blockIdx.x >= 2) return;
    int t = z - 3;
    A = absb + (size_t)(t >> 1)*524288;
    Bt = Wp + (size_t)t*65536;
    bias = bqk + t*128;
    C = Pqk + (size_t)t*131072; ldc = 128;
  }
  gemm64_body<false,false>(smem, A, 512, Bt, 512, bias, C, ldc, 8,
      blockIdx.y*64, blockIdx.x*64);
}

// ---------------- fused pre-attention ---------------------------------------
// blocks 0..255:    u = (Xq+rel_bias) @ Wrk^T (64^2 tiles, A inline from q)
// blocks 256..1279: Pqk += head slices of q/k
// blocks 1280..2303: cvec = brk . (Xq+rel_bias)
__global__ __launch_bounds__(256) void fused_pre(
    const float* __restrict__ q, const float* __restrict__ k,
    float* __restrict__ Pqk, const float* __restrict__ rel_bias,
    const float* __restrict__ brk, const ushort* __restrict__ Wrkb,
    float* __restrict__ u, float* __restrict__ cvec)
{
  int blk = blockIdx.x;
  int tid = threadIdx.x;
  if (blk < 256) {
    int l = blk >> 7;
    int rem = blk & 127;
    int bm = (rem >> 3) * 64;     // 16 m-tiles
    int bn = (rem & 7) * 64;      // 8 n-tiles
    __shared__ __align__(16) char smem[16384];
    char* asB = smem;
    char* bsB = smem + 8192;
    int lane = tid & 63, wid = tid >> 6;
    int wr = wid >> 1, wc = wid & 1;
    int l15 = lane & 15, kg = lane >> 4;
    f32x4 acc[2][2] = {};
    const ushort* Bb = Wrkb + (size_t)l*65536 + (size_t)bn*128;
    int r0 = tid >> 3, c16 = tid & 7;
    int wb0 = r0*128 + ((c16*16) ^ ((r0 & 7) << 4));
    int wb1 = (r0+32)*128 + ((c16*16) ^ ((r0 & 7) << 4));
    const float* rbp = rel_bias + l*128;
    #pragma unroll
    for (int ks = 0; ks < 2; ++ks) {
      int k0 = ks * 64;
      int e0 = k0 + c16*8;
      uint4 ra[2], rb[2];
      #pragma unroll
      for (int i = 0; i < 2; ++i) {
        int m = bm + r0 + i*32;
        const float* qp = q + (size_t)m*512 + (2+l)*128 + e0;
        float4 qa = *(const float4*)qp;
        float4 qb = *(const float4*)(qp + 4);
        float4 rr0 = *(const float4*)(rbp + e0);
        float4 rr1 = *(const float4*)(rbp + e0 + 4);
        union { ushort s[8]; uint4 v; } pk;
        pk.s[0]=f2bf(qa.x+rr0.x); pk.s[1]=f2bf(qa.y+rr0.y);
        pk.s[2]=f2bf(qa.z+rr0.z); pk.s[3]=f2bf(qa.w+rr0.w);
        pk.s[4]=f2bf(qb.x+rr1.x); pk.s[5]=f2bf(qb.y+rr1.y);
        pk.s[6]=f2bf(qb.z+rr1.z); pk.s[7]=f2bf(qb.w+rr1.w);
        ra[i] = pk.v;
        rb[i] = *(const uint4*)(Bb + (size_t)(r0 + i*32)*128 + k0 + c16*8);
      }
      __syncthreads();
      *(uint4*)(asB + wb0) = ra[0];  *(uint4*)(asB + wb1) = ra[1];
      *(uint4*)(bsB + wb0) = rb[0];  *(uint4*)(bsB + wb1) = rb[1];
      __syncthreads();
      #pragma unroll
      for (int half = 0; half < 2; ++half) {
        int cb = half*64 + kg*16;
        short8v av[2], bv[2];
        #pragma unroll
        for (int m = 0; m < 2; ++m) {
          int r = wr*32 + m*16 + l15;
          av[m] = *(const short8v*)(asB + r*128 + (cb ^ ((r & 7) << 4)));
        }
        #pragma unroll
        for (int n = 0; n < 2; ++n) {
          int r = wc*32 + n*16 + l15;
          bv[n] = *(const short8v*)(bsB + r*128 + (cb ^ ((r & 7) << 4)));
        }
        #pragma unroll
        for (int m = 0; m < 2; ++m)
          #pragma unroll
          for (int n = 0; n < 2; ++n)
            acc[m][n] = __builtin_amdgcn_mfma_f32_16x16x32_bf16(av[m], bv[n], acc[m][n], 0, 0, 0);
      }
    }
    float* Cz = u + (size_t)l*524288;
    int orow0 = bm + wr*32 + kg*4;
    int ocol0 = bn + wc*32 + l15;
    #pragma unroll
    for (int m = 0; m < 2; ++m)
      #pragma unroll
      for (int r = 0; r < 4; ++r) {
        int row = orow0 + m*16 + r;
        #pragma unroll
        for (int n = 0; n < 2; ++n)
          Cz[(size_t)row*512 + ocol0 + n*16] = acc[m][n][r];
      }
  } else if (blk < 1280) {
    int idx = (blk - 256)*256 + tid;
    int dk = idx & 127;
    int rest = idx >> 7;
    int m = rest & 1023;
    int a = rest >> 10;
    Pqk[idx + a*131072]     += q[(size_t)m*512 + a*128 + dk];
    Pqk[idx + (a+1)*131072] += k[(size_t)m*512 + a*128 + dk];
  } else {
    int row = (blk - 1280)*2 + (tid >> 7);
    int l = row >> 10, m = row & 1023;
    int t = tid & 127, hf = tid >> 7;
    float val = q[(size_t)m*512 + (2+l)*128 + t] + rel_bias[l*128 + t];
    float p = brk[l*128 + t] * val;
    #pragma unroll
    for (int off = 32; off > 0; off >>= 1) p += __shfl_xor(p, off);
    __shared__ float red[2][2];
    if ((tid & 63) == 0) red[hf][(tid >> 6) & 1] = p;
    __syncthreads();
    if (t == 0) cvec[row] = red[hf][0] + red[hf][1];
  }
}

// -------- fused attention: rel stream | abs heads | deferred transposes ----
__global__ __launch_bounds__(256) void attn_kernel(
    const float* __restrict__ rk, const float* __restrict__ u,
    const float* __restrict__ q, const float* __restrict__ k,
    const float* __restrict__ v, const float* __restrict__ cvec,
    const float* __restrict__ Pqk, const int* __restrict__ mask,
    ushort* __restrict__ attnob,
    const float* __restrict__ Wo, ushort* __restrict__ WoT,
    const float* __restrict__ W1, ushort* __restrict__ W1T,
    const float* __restrict__ W2, ushort* __restrict__ W2T)
{
  __shared__ __align__(16) char shm[8448];
  int blk = blockIdx.x;
  int tid = threadIdx.x;
  if (blk < 2048) {
    struct RelShm { float qs[128], sc[128], ps[128], red[64], pvs[2][128], stat[2]; };
    RelShm* S = (RelShm*)shm;
    int i = blk & 127, b = (blk >> 7) & 7, l = blk >> 10, h = 2 + l;
    int m_i = b*128 + i;
    int wave = tid >> 6, lane = tid & 63;
    const float* ur = u + ((size_t)l*1024 + m_i)*512 + lane*8;
    float4 uu0 = *(const float4*)ur;
    float4 uu1 = *(const float4*)(ur + 4);
    if (tid < 128) S->qs[tid] = q[(size_t)m_i*512 + h*128 + tid];
    __syncthreads();
    float xq0 = S->qs[lane*2], xq1 = S->qs[lane*2+1];
    const float* base = rk + (size_t)blk*65536 + lane*8;
    const float* kb = k + (size_t)(b*128)*512 + h*128 + lane*2;
    #pragma unroll 2
    for (int jj = 0; jj < 32; ++jj) {
      int j = wave*32 + jj;
      const float* r = base + (size_t)j*512;
      float4 r0 = *(const float4*)r;
      float4 r1 = *(const float4*)(r + 4);
      float2 kk = *(const float2*)(kb + (size_t)j*512);
      float s = r0.x*uu0.x + r0.y*uu0.y + r0.z*uu0.z + r0.w*uu0.w
              + r1.x*uu1.x + r1.y*uu1.y + r1.z*uu1.z + r1.w*uu1.w
              + kk.x*xq0 + kk.y*xq1;
      #pragma unroll
      for (int off = 32; off > 0; off >>= 1) s += __shfl_xor(s, off);
      if (lane == 0) S->sc[j] = s;
    }
    __syncthreads();
    if (tid < 128) {
      float sv = (S->sc[tid] + cvec[l*1024 + m_i]) * 0.088388347648318447f;
      if (mask[((size_t)(b*128) + i)*128 + tid] == 0) sv = -1e9f;
      S->sc[tid] = sv;
    }
    __syncthreads();
    if (tid < 64) S->red[tid] = fmaxf(S->sc[tid], S->sc[tid+64]);
    __syncthreads();
    if (tid < 64) {
      float m = S->red[tid];
      #pragma unroll
      for (int off = 32; off > 0; off >>= 1) m = fmaxf(m, __shfl_xor(m, off));
      if (tid == 0) S->stat[0] = m;
    }
    __syncthreads();
    if (tid < 128) S->ps[tid] = __expf(S->sc[tid] - S->stat[0]);
    __syncthreads();
    if (tid < 64) S->red[tid] = S->ps[tid] + S->ps[tid+64];
    __syncthreads();
    if (tid < 64) {
      float s = S->red[tid];
      #pragma unroll
      for (int off = 32; off > 0; off >>= 1) s += __shfl_xor(s, off);
      if (tid == 0) S->stat[1] = 1.0f / s;
    }
    __syncthreads();
    int hf = tid >> 7, dk = tid & 127;
    const float* vp = v + (size_t)(b*128 + hf*64)*512 + h*128 + dk;
    float o = 0.0f;
    #pragma unroll 4
    for (int jj = 0; jj < 64; ++jj) o += S->ps[hf*64 + jj] * vp[(size_t)jj*512];
    S->pvs[hf][dk] = o;
    __syncthreads();
    if (tid < 128)
      attnob[(size_t)m_i*512 + h*128 + tid] = f2bf((S->pvs[0][tid] + S->pvs[1][tid]) * S->stat[1]);
  } else if (blk < 3072) {
    struct AbsShm { float qsh[2][128], psh[2][128], redm[2][2], reds[2][2]; };
    AbsShm* S = (AbsShm*)shm;
    int ab = blk - 2048;
    int hf = tid >> 7, t = tid & 127;
    int i  = (ab & 63)*2 + hf;
    int bh = ab >> 6;
    int h  = bh & 1, b = bh >> 1;
    int m_i = b*128 + i;
    S->qsh[hf][t] = Pqk[(size_t)(2*h)*131072 + (size_t)m_i*128 + t];
    __syncthreads();
    int m_j = b*128 + t;
    const float* krow = Pqk + (size_t)(2*h+1)*131072 + (size_t)m_j*128;
    float dot = 0.0f;
    #pragma unroll
    for (int d = 0; d < 128; d += 4) {
      float4 kv = *(const float4*)(krow + d);
      dot += kv.x*S->qsh[hf][d] + kv.y*S->qsh[hf][d+1] + kv.z*S->qsh[hf][d+2] + kv.w*S->qsh[hf][d+3];
    }
    float s = dot * 0.088388347648318447f;
    if (mask[((size_t)(b*128) + i)*128 + t] == 0) s = -1e9f;
    float mx = s;
    #pragma unroll
    for (int off = 32; off > 0; off >>= 1) mx = fmaxf(mx, __shfl_xor(mx, off));
    int w2 = (tid >> 6) & 1;
    if ((tid & 63) == 0) S->redm[hf][w2] = mx;
    __syncthreads();
    mx = fmaxf(S->redm[hf][0], S->redm[hf][1]);
    float e = __expf(s - mx);
    S->psh[hf][t] = e;
    float sum = e;
    #pragma unroll
    for (int off = 32; off > 0; off >>= 1) sum += __shfl_xor(sum, off);
    if ((tid & 63) == 0) S->reds[hf][w2] = sum;
    __syncthreads();
    float inv = 1.0f / (S->reds[hf][0] + S->reds[hf][1]);
    const float* vp = v + (size_t)b*65536 + h*128 + t;
    float o = 0.0f;
    #pragma unroll 4
    for (int jj = 0; jj < 128; ++jj) o += S->psh[hf][jj] * vp[(size_t)jj*512];
    attnob[(size_t)m_i*512 + h*128 + t] = f2bf(o * inv);
  } else {
    // deferred weight transposes (needed only after attention)
    int t2 = blk - 3072;
    if (t2 < 64)       transpose_tile(shm, Wo, WoT, 512, 512, t2);
    else if (t2 < 320) transpose_tile(shm, W1, W1T, 512, 2048, t2 - 64);
    else               transpose_tile(shm, W2, W2T, 2048, 512, t2 - 320);
  }
}

// ---------------- split-K reduce (Wo) + bias + residual + LN2 --------------
__global__ __launch_bounds__(256) void reduce_ln_kernel(
    const float* __restrict__ wpart, const float* __restrict__ bo,
    const float* __restrict__ x, const float* __restrict__ g,
    const float* __restrict__ bb, float* __restrict__ x1,
    ushort* __restrict__ h2)
{
  int gid = blockIdx.x*256 + threadIdx.x;
  int row = gid >> 6, lane = threadIdx.x & 63;
  size_t off = (size_t)row*512 + lane*8;
  float4 a = *(const float4*)(x + off);
  float4 c = *(const float4*)(x + off + 4);
  #pragma unroll
  for (int sk = 0; sk < 4; ++sk) {
    float4 p0 = *(const float4*)(wpart + (size_t)sk*524288 + off);
    float4 p1 = *(const float4*)(wpart + (size_t)sk*524288 + off + 4);
    a.x += p0.x; a.y += p0.y; a.z += p0.z; a.w += p0.w;
    c.x += p1.x; c.y += p1.y; c.z += p1.z; c.w += p1.w;
  }
  float4 bo0 = *(const float4*)(bo + lane*8);
  float4 bo1 = *(const float4*)(bo + lane*8 + 4);
  a.x += bo0.x; a.y += bo0.y; a.z += bo0.z; a.w += bo0.w;
  c.x += bo1.x; c.y += bo1.y; c.z += bo1.z; c.w += bo1.w;
  *(float4*)(x1 + off) = a;
  *(float4*)(x1 + off + 4) = c;
  float s  = a.x + a.y + a.z + a.w + c.x + c.y + c.z + c.w;
  float ss = a.x*a.x + a.y*a.y + a.z*a.z + a.w*a.w
           + c.x*c.x + c.y*c.y + c.z*c.z + c.w*c.w;
  #pragma unroll
  for (int off2 = 32; off2 > 0; off2 >>= 1) {
    s  += __shfl_xor(s, off2);
    ss += __shfl_xor(ss, off2);
  }
  float mu  = s * (1.0f/512.0f);
  float var = ss * (1.0f/512.0f) - mu*mu;
  float rstd = rsqrtf(var + 1e-5f);
  float4 g0 = *(const float4*)(g + lane*8), g1 = *(const float4*)(g + lane*8 + 4);
  float4 b0 = *(const float4*)(bb + lane*8), b1 = *(const float4*)(bb + lane*8 + 4);
  union { ushort u[8]; uint4 v; } pk;
  pk.u[0] = f2bf((a.x-mu)*rstd*g0.x + b0.x);
  pk.u[1] = f2bf((a.y-mu)*rstd*g0.y + b0.y);
  pk.u[2] = f2bf((a.z-mu)*rstd*g0.z + b0.z);
  pk.u[3] = f2bf((a.w-mu)*rstd*g0.w + b0.w);
  pk.u[4] = f2bf((c.x-mu)*rstd*g1.x + b1.x);
  pk.u[5] = f2bf((c.y-mu)*rstd*g1.y + b1.y);
  pk.u[6] = f2bf((c.z-mu)*rstd*g1.z + b1.z);
  pk.u[7] = f2bf((c.w-mu)*rstd*g1.w + b1.w);
  *(uint4*)(h2 + off) = pk.v;
}

// ---------------- split-K reduce (FFN2) + bias + residual -> out -----------
__global__ __launch_bounds__(256) void reduce_out_kernel(
    const float* __restrict__ fpart, const float* __restrict__ b2,
    const float* __restrict__ x1, float* __restrict__ out)
{
  int idx = blockIdx.x*256 + threadIdx.x;
  size_t o4 = (size_t)idx*4;
  float4 s = *(const float4*)(x1 + o4);
  #pragma unroll
  for (int sk = 0; sk < 4; ++sk) {
    float4 p = *(const float4*)(fpart + (size_t)sk*524288 + o4);
    s.x += p.x; s.y += p.y; s.z += p.z; s.w += p.w;
  }
  float4 bv = *(const float4*)(b2 + ((idx & 127)*4));
  s.x += bv.x; s.y += bv.y; s.z += bv.z; s.w += bv.w;
  *(float4*)(out + o4) = s;
}

// ---------------------------------------------------------------------------
extern "C" void kernel_launch(void* const* d_in, const int* in_sizes, int n_in,
                              void* d_out, int out_size, void* d_ws, size_t ws_size,
                              hipStream_t stream)
{
  const float* x         = (const float*)d_in[0];
  const int*   mask      = (const int*)  d_in[1];
  const float* abs_kernel= (const float*)d_in[2];
  const float* rel_kernel= (const float*)d_in[3];
  const float* Wc        = (const float*)d_in[4];
  const float* bc        = (const float*)d_in[5];
  const float* Wpq       = (const float*)d_in[6];
  const float* bpq       = (const float*)d_in[7];
  const float* Wpk       = (const float*)d_in[8];
  const float* bpk       = (const float*)d_in[9];
  const float* Wrk       = (const float*)d_in[10];
  const float* brk       = (const float*)d_in[11];
  const float* rel_bias  = (const float*)d_in[12];
  const float* Wo        = (const float*)d_in[13];
  const float* bo        = (const float*)d_in[14];
  const float* W1        = (const float*)d_in[15];
  const float* b1        = (const float*)d_in[16];
  const float* W2        = (const float*)d_in[17];
  const float* b2        = (const float*)d_in[18];
  const float* ln1g      = (const float*)d_in[19];
  const float* ln1b      = (const float*)d_in[20];
  const float* ln2g      = (const float*)d_in[21];
  const float* ln2b      = (const float*)d_in[22];

  float* ws = (float*)d_ws;
  float* q      = ws;               // 3x524288 (q|k|v)
  float* kbuf   = ws + 524288;
  float* v      = ws + 1048576;
  float* Pqk    = ws + 1572864;     // 524288
  float* u      = ws + 2097152;     // 1048576
  float* x1     = ws + 3145728;     // 524288
  float* cvec   = ws + 3670016;     // 2048
  float* bqk    = ws + 3672064;     // 512
  float* wpart  = ws + 3672576;     // 2097152 (reused as fpart)
  float* fpart  = wpart;
  ushort* bf    = (ushort*)(ws + 5769728);
  ushort* h     = bf;               // 524288
  ushort* h2    = bf + 524288;
  ushort* attnob= bf + 1048576;     // 524288
  ushort* f1    = bf + 1572864;     // 2097152
  ushort* absb  = bf + 3670016;     // 1048576
  ushort* WcT   = bf + 4718592;     // 786432
  ushort* Wp    = bf + 5505024;     // 262144
  ushort* Wrkb  = bf + 5767168;     // 131072
  ushort* WoT   = bf + 5898240;     // 262144
  ushort* W1T   = bf + 6160384;     // 1048576
  ushort* W2T   = bf + 7208960;     // 1048576
  float* out    = (float*)d_out;

  // ---- early convert/transpose/LN task table (Wo/W1/W2 deferred to attn) --
  CvtTasks T{};
  int nb = 0, ti = 0;
  auto addTr = [&](const float* s, ushort* d, int R, int C) {
    T.src[ti]=s; T.dst[ti]=d; T.rows[ti]=R; T.cols[ti]=C; T.mode[ti]=0; T.aux[ti]=0;
    nb += (R/64)*(C/64); T.end[ti]=nb; ++ti;
  };
  auto addCv = [&](const float* s, ushort* d, int n) {
    T.src[ti]=s; T.dst[ti]=d; T.rows[ti]=n; T.cols[ti]=0; T.mode[ti]=1; T.aux[ti]=0;
    nb += n/2048; T.end[ti]=nb; ++ti;
  };
  auto addBi = [&](const float* s, float* d, int aux) {
    T.src[ti]=s; T.dst[ti]=d; T.rows[ti]=2; T.cols[ti]=128; T.mode[ti]=2; T.aux[ti]=aux;
    nb += 1; T.end[ti]=nb; ++ti;
  };
  for (int c = 0; c < 3; ++c) addTr(Wc + (size_t)c*262144, WcT + (size_t)c*262144, 512, 512);
  for (int a = 0; a < 2; ++a) addTr(Wpq + (size_t)a*65536, Wp + (size_t)(2*a)*65536, 512, 128);
  for (int a = 0; a < 2; ++a) addTr(Wpk + (size_t)a*65536, Wp + (size_t)(2*a+1)*65536, 512, 128);
  addCv(abs_kernel, absb, 1048576);
  addCv(Wrk, Wrkb, 131072);
  addBi(bpq, bqk, 0);
  addBi(bpk, bqk, 1);
  T.src[ti]=x; T.dst[ti]=h; T.mode[ti]=3; nb += 256; T.end[ti]=nb; ++ti;

  cvt_kernel<<<nb, 256, 0, stream>>>(T, x, ln1g, ln1b, h);

  // grouped qkv + Pqk (512 useful 64^2 blocks)
  qkvp_gemm<<<dim3(8,16,7), 256, 0, stream>>>(h, WcT, bc, q, absb, Wp, bqk, Pqk);

  // fused: u-GEMM (inline uin) + addhead + cvec
  fused_pre<<<2304, 256, 0, stream>>>(q, kbuf, Pqk, rel_bias, brk, Wrkb, u, cvec);

  // fused attention: rel stream + abs heads + deferred weight transposes
  attn_kernel<<<3648, 256, 0, stream>>>(rel_kernel, u, q, kbuf, v, cvec, Pqk,
                                        mask, attnob, Wo, WoT, W1, W1T, W2, W2T);

  // Wo projection split-K 4 -> wpart
  g64<false,false><<<dim3(8,16,4), 256, 0, stream>>>(
      attnob, 512, 128, WoT, 512, 128, nullptr, 0, wpart, 512, 524288, 2);

  // reduce + bo + residual(x) + LN2 -> x1, h2
  reduce_ln_kernel<<<256, 256, 0, stream>>>(wpart, bo, x, ln2g, ln2b, x1, h2);

  // FFN1 + GELU -> f1 (bf16)
  g64<true,true><<<dim3(32,16,1), 256, 0, stream>>>(
      h2, 512, 0, W1T, 512, 0, b1, 0, f1, 2048, 0, 8);

  // FFN2 split-K 4 -> fpart
  g64<false,false><<<dim3(8,16,4), 256, 0, stream>>>(
      f1, 2048, 512, W2T, 2048, 512, nullptr, 0, fpart, 512, 524288, 8);

  // reduce + b2 + residual(x1) -> out
  reduce_out_kernel<<<512, 256, 0, stream>>>(fpart, b2, x1, out);
}